// Round 19
// baseline (87.912 us; speedup 1.0000x reference)
//
#include <hip/hip_runtime.h>
#include <hip/hip_bf16.h>
#include <stdint.h>

// Problem constants (fixed by setup_inputs)
#define Bn 64
#define Sn 2048
#define Dn 768
#define An 256
#define EPSF 1e-7f
#define ROWS 32              // s-rows per chunk
#define NK (Dn / 32)         // 24 K-steps of 32

typedef __bf16 bf16x8 __attribute__((ext_vector_type(8)));
typedef float f32x4 __attribute__((ext_vector_type(4)));

// ---------------- merged prep: pack W + compact mask (one launch) ----------------
// blocks 0..95: pack W -> bf16 MFMA-B-fragment layout (4 (kk,cb) jobs/block).
//   packed[((kk*16+cb)*64+l)*8+e] = bf16( W[kk*32+(l>>4)*8+e][cb*16+(l&15)] )
// blocks 96..159: per-batch deterministic prefix-scan compaction of mask.
__global__ void prep_kernel(const float* __restrict__ W, unsigned short* __restrict__ pw,
                            const int* __restrict__ mask,
                            int* __restrict__ ridx, int* __restrict__ count) {
  const int bid = blockIdx.x;
  const int tid = threadIdx.x;
  if (bid < 96) {
    int job = bid * 4 + (tid >> 6);   // 0..383
    int l   = tid & 63;
    int kk  = job >> 4;               // 0..23
    int cb  = job & 15;               // 0..15
    int a   = cb * 16 + (l & 15);
    int k0  = kk * 32 + (l >> 4) * 8;
    bf16x8 pk;
#pragma unroll
    for (int j = 0; j < 8; ++j) pk[j] = (__bf16)W[(k0 + j) * An + a];
    *(bf16x8*)(pw + ((size_t)(job * 64 + l)) * 8) = pk;
  } else {
    __shared__ int scan[256];
    const int b = bid - 96;
    const int* mrow = mask + (size_t)b * Sn;
    int loc[8], lc = 0;
#pragma unroll
    for (int k = 0; k < 8; ++k) {
      loc[k] = mrow[tid * 8 + k];
      lc += loc[k];
    }
    scan[tid] = lc;
    __syncthreads();
    for (int off = 1; off < 256; off <<= 1) {
      int v = scan[tid];
      int add = (tid >= off) ? scan[tid - off] : 0;
      __syncthreads();
      scan[tid] = v + add;
      __syncthreads();
    }
    int o = scan[tid] - lc;           // exclusive prefix
    int* rb = ridx + (size_t)b * Sn;
#pragma unroll
    for (int k = 0; k < 8; ++k)
      if (loc[k]) rb[o++] = tid * 8 + k;
    if (tid == 255) count[b] = scan[255];
  }
}

// ---------------- main fused kernel (R18 + depth-6 wf + barrier-free row gather) ----
// grid = 4096 slots; slot (b, ci) processes active rows [ci*32, ci*32+32).
// Staging: batch-issued 24 float4/thread (R11-proven); per-thread row indices
// read directly from ridx (32 distinct ints, L2 broadcast) -> no pre-stage
// barrier, HBM stream starts immediately.
// K-loop: wf[6][4] depth-6 W register rotation -> issue->use distance 20
// loads (~5 K-steps) fully covers ~250cy L2 latency.
__launch_bounds__(256, 3)
__global__ void attn_pool_main(const float* __restrict__ x,
                               const unsigned short* __restrict__ pw,
                               const float* __restrict__ bias,
                               const float* __restrict__ u,
                               const int* __restrict__ ridx,
                               const int* __restrict__ count,
                               float* __restrict__ outpart,
                               float* __restrict__ sumpart) {
  __shared__ __align__(16) char xs[49152];   // 32 rows x 768 bf16, XOR-swizzled
  __shared__ float aitp[128];
  __shared__ float aitv[32];

  const int tid  = threadIdx.x;
  const int lane = tid & 63;
  const int w    = tid >> 6;      // wave 0..3, cols w*64..w*64+63
  const int cid  = blockIdx.x;
  const int b    = cid >> 6;
  const int ci   = cid & 63;
  const int base = ci * ROWS;
  const int ntot = count[b];
  if (base >= ntot) return;                    // inactive slot
  const int nact = min(ROWS, ntot - base);

  // ---- stage x tile: 32 gathered rows x 768 fp32 -> bf16 LDS (swizzled) ----
  // Row indices fetched per-thread straight from ridx (no LDS, no barrier).
  const float* xbb = x + (size_t)b * Sn * Dn;
  const int* rb = ridx + (size_t)b * Sn + base;
  {
    float4 ldA[12], ldB[12];
#pragma unroll
    for (int j = 0; j < 12; ++j) {
      int unit = tid + j * 256;       // 0..3071 ; 8 k-elems each
      int row  = unit / 96;
      int ku   = unit % 96;
      int grow = rb[(row < nact) ? row : 0];
      const float4* g = (const float4*)(xbb + (size_t)grow * Dn + ku * 8);
      ldA[j] = g[0];
      ldB[j] = g[1];
    }
    __builtin_amdgcn_sched_barrier(0);   // keep all 24 loads issued up-front
#pragma unroll
    for (int j = 0; j < 12; ++j) {
      int unit = tid + j * 256;
      int row  = unit / 96;
      int ku   = unit % 96;
      bf16x8 pk;
      pk[0] = (__bf16)ldA[j].x; pk[1] = (__bf16)ldA[j].y;
      pk[2] = (__bf16)ldA[j].z; pk[3] = (__bf16)ldA[j].w;
      pk[4] = (__bf16)ldB[j].x; pk[5] = (__bf16)ldB[j].y;
      pk[6] = (__bf16)ldB[j].z; pk[7] = (__bf16)ldB[j].w;
      int off = (row * 1536 + ku * 16) ^ ((row & 7) << 4);
      *(bf16x8*)(xs + off) = pk;
    }
  }

  const int arow  = lane & 15;
  const int kh16  = (lane >> 4) * 16;
  const int swz   = (arow & 7) << 4;
  const char* wlane = (const char*)pw + (size_t)(w * 4) * 1024 + (size_t)lane * 16;

  // ---- W pipeline prologue: load kk=0..5 into wf (ld regs dead now) ----
  bf16x8 wf[6][4];
#pragma unroll
  for (int s = 0; s < 6; ++s) {
    const char* wk = wlane + (size_t)s * 16384;
    wf[s][0] = *(const bf16x8*)(wk);
    wf[s][1] = *(const bf16x8*)(wk + 1024);
    wf[s][2] = *(const bf16x8*)(wk + 2048);
    wf[s][3] = *(const bf16x8*)(wk + 3072);
  }

  asm volatile("s_waitcnt lgkmcnt(0)" ::: "memory");
  __builtin_amdgcn_s_barrier();     // xs published; wf stream in flight

  f32x4 acc[2][4];
#pragma unroll
  for (int p = 0; p < 2; ++p)
#pragma unroll
    for (int q = 0; q < 4; ++q) acc[p][q] = (f32x4){0.f, 0.f, 0.f, 0.f};

  // ---- K-loop: use wf[kk%6], reload it for kk+6 (counted vmcnt waits) ----
#pragma unroll
  for (int kk = 0; kk < NK; ++kk) {
    const int s = kk % 6;
    bf16x8 a0 = *(const bf16x8*)(xs + ((arow * 1536 + kk * 64 + kh16) ^ swz));
    bf16x8 a1 = *(const bf16x8*)(xs + (((arow + 16) * 1536 + kk * 64 + kh16) ^ swz));
    bf16x8 b0 = wf[s][0], b1 = wf[s][1], b2 = wf[s][2], b3 = wf[s][3];
    if (kk + 6 < NK) {
      const char* wk = wlane + (size_t)(kk + 6) * 16384;
      wf[s][0] = *(const bf16x8*)(wk);
      wf[s][1] = *(const bf16x8*)(wk + 1024);
      wf[s][2] = *(const bf16x8*)(wk + 2048);
      wf[s][3] = *(const bf16x8*)(wk + 3072);
    }
    acc[0][0] = __builtin_amdgcn_mfma_f32_16x16x32_bf16(a0, b0, acc[0][0], 0, 0, 0);
    acc[1][0] = __builtin_amdgcn_mfma_f32_16x16x32_bf16(a1, b0, acc[1][0], 0, 0, 0);
    acc[0][1] = __builtin_amdgcn_mfma_f32_16x16x32_bf16(a0, b1, acc[0][1], 0, 0, 0);
    acc[1][1] = __builtin_amdgcn_mfma_f32_16x16x32_bf16(a1, b1, acc[1][1], 0, 0, 0);
    acc[0][2] = __builtin_amdgcn_mfma_f32_16x16x32_bf16(a0, b2, acc[0][2], 0, 0, 0);
    acc[1][2] = __builtin_amdgcn_mfma_f32_16x16x32_bf16(a1, b2, acc[1][2], 0, 0, 0);
    acc[0][3] = __builtin_amdgcn_mfma_f32_16x16x32_bf16(a0, b3, acc[0][3], 0, 0, 0);
    acc[1][3] = __builtin_amdgcn_mfma_f32_16x16x32_bf16(a1, b3, acc[1][3], 0, 0, 0);
  }

  // ---- epilogue: tanh + dot with u -> per-row partials ----
  float rowp[8];
#pragma unroll
  for (int p = 0; p < 8; ++p) rowp[p] = 0.f;
#pragma unroll
  for (int cbi = 0; cbi < 4; ++cbi) {
    int col = w * 64 + cbi * 16 + arow;
    float bia = bias[col];
    float uv  = u[col];
#pragma unroll
    for (int rb2 = 0; rb2 < 2; ++rb2) {
#pragma unroll
      for (int r = 0; r < 4; ++r) {
        float v = acc[rb2][cbi][r] + bia;
        v = fminf(fmaxf(v, -15.f), 15.f);
        float e2 = __expf(2.f * v);
        float th = (e2 - 1.f) * __builtin_amdgcn_rcpf(e2 + 1.f);
        rowp[rb2 * 4 + r] += th * uv;
      }
    }
  }
#pragma unroll
  for (int m = 1; m < 16; m <<= 1)
#pragma unroll
    for (int p = 0; p < 8; ++p) rowp[p] += __shfl_xor(rowp[p], m, 64);

  if (arow == 0) {
    int rbase = (lane >> 4) * 4;
#pragma unroll
    for (int rb2 = 0; rb2 < 2; ++rb2)
#pragma unroll
      for (int r = 0; r < 4; ++r)
        aitp[w * 32 + rb2 * 16 + rbase + r] = rowp[rb2 * 4 + r];
  }
  __syncthreads();

  // ---- ait = exp(sum) for active rows, 0 for pad ; chunk sum ----
  if (tid < 32) {
    float s = aitp[tid] + aitp[32 + tid] + aitp[64 + tid] + aitp[96 + tid];
    float av = (tid < nact) ? __expf(s) : 0.f;
    aitv[tid] = av;
    float t = av;
#pragma unroll
    for (int m = 1; m < 32; m <<= 1) t += __shfl_xor(t, m, 64);
    if (tid == 0) sumpart[cid] = t;
  }
  __syncthreads();

  // ---- pooling: 192 threads, 2 row-groups of 16 rows ----
  float pac[8];
#pragma unroll
  for (int e = 0; e < 8; ++e) pac[e] = 0.f;
  int rg = tid / 96;              // 0..1 for tid<192
  int du = tid % 96;              // 8-d unit
  if (tid < 192) {
#pragma unroll
    for (int rr = 0; rr < 16; ++rr) {
      int row = rg * 16 + rr;
      int off = (row * 1536 + du * 16) ^ ((row & 7) << 4);
      bf16x8 xv = *(const bf16x8*)(xs + off);
      float a = aitv[row];
#pragma unroll
      for (int e = 0; e < 8; ++e) pac[e] += a * (float)xv[e];
    }
  }
  __syncthreads();   // all xs reads done -> safe to overlay outred onto xs

  float* outred = (float*)xs;     // [2][768] overlay
  if (tid < 192) {
#pragma unroll
    for (int e = 0; e < 8; ++e) outred[rg * 768 + du * 8 + e] = pac[e];
  }
  __syncthreads();

  {
    float* op = outpart + (size_t)cid * Dn;
#pragma unroll
    for (int j = 0; j < 3; ++j) {
      int d = tid + j * 256;
      op[d] = outred[d] + outred[768 + d];
    }
  }
}

// ---------------- finalize: out[b,d] = sum over written chunks / (sum + eps) ----
// grid = 64 b x 12 slabs of 64 d; 4 c-groups per block -> <=16 independent
// strided loads per thread (latency-hidden), then 4-way LDS reduce.
__global__ void finalize_kernel(const float* __restrict__ outpart,
                                const float* __restrict__ sumpart,
                                const int* __restrict__ count,
                                float* __restrict__ out) {
  __shared__ float red[4][64];
  __shared__ float sh;
  int b = blockIdx.x / 12, slab = blockIdx.x % 12;
  int tid = threadIdx.x;
  const int nch = (count[b] + ROWS - 1) / ROWS;   // written chunk slots
  if (tid < 64) {
    float v = (tid < nch) ? sumpart[b * 64 + tid] : 0.f;
#pragma unroll
    for (int m = 1; m < 64; m <<= 1) v += __shfl_xor(v, m, 64);
    if (tid == 0) sh = v + EPSF;
  }
  int d  = slab * 64 + (tid & 63);
  int cg = tid >> 6;                // 0..3
  const float* p = outpart + (size_t)b * 64 * Dn + d;
  float s = 0.f;
  for (int c = cg; c < nch; c += 4) s += p[(size_t)c * Dn];
  red[cg][tid & 63] = s;
  __syncthreads();
  if (tid < 64) {
    float tot = red[0][tid] + red[1][tid] + red[2][tid] + red[3][tid];
    out[(size_t)b * Dn + d] = tot / sh;
  }
}

extern "C" void kernel_launch(void* const* d_in, const int* in_sizes, int n_in,
                              void* d_out, int out_size, void* d_ws, size_t ws_size,
                              hipStream_t stream) {
  const float* x    = (const float*)d_in[0];
  const float* W    = (const float*)d_in[1];
  const float* bias = (const float*)d_in[2];
  const float* u    = (const float*)d_in[3];
  const int*   mask = (const int*)d_in[4];
  float* out = (float*)d_out;

  unsigned short* pw = (unsigned short*)d_ws;                       // 384 KB
  float* outpart = (float*)((char*)d_ws + 393216);                  // 12.58 MB
  float* sumpart = (float*)((char*)d_ws + 393216 + 12582912);       // 16 KB
  int*   ridx    = (int*)((char*)d_ws + 393216 + 12582912 + 16384); // 512 KB
  int*   count   = (int*)((char*)d_ws + 393216 + 12582912 + 16384 + 524288); // 256 B

  hipLaunchKernelGGL(prep_kernel, dim3(160), dim3(256), 0, stream,
                     W, pw, mask, ridx, count);
  hipLaunchKernelGGL(attn_pool_main, dim3(Bn * 64), dim3(256), 0, stream,
                     x, pw, bias, u, ridx, count, outpart, sumpart);
  hipLaunchKernelGGL(finalize_kernel, dim3(Bn * 12), dim3(256), 0, stream,
                     outpart, sumpart, count, out);
}

// Round 20
// 82.991 us; speedup vs baseline: 1.0593x; 1.0593x over previous
//
#include <hip/hip_runtime.h>
#include <hip/hip_bf16.h>
#include <stdint.h>

// Problem constants (fixed by setup_inputs)
#define Bn 64
#define Sn 2048
#define Dn 768
#define An 256
#define EPSF 1e-7f
#define ROWS 32              // s-rows per chunk
#define NK (Dn / 32)         // 24 K-steps of 32

typedef __bf16 bf16x8 __attribute__((ext_vector_type(8)));
typedef float f32x4 __attribute__((ext_vector_type(4)));

// ---------------- merged prep: pack W + compact mask (one launch) ----------------
// blocks 0..95: pack W -> bf16 MFMA-B-fragment layout (4 (kk,cb) jobs/block).
//   packed[((kk*16+cb)*64+l)*8+e] = bf16( W[kk*32+(l>>4)*8+e][cb*16+(l&15)] )
// blocks 96..159: per-batch deterministic prefix-scan compaction of mask.
__global__ void prep_kernel(const float* __restrict__ W, unsigned short* __restrict__ pw,
                            const int* __restrict__ mask,
                            int* __restrict__ ridx, int* __restrict__ count) {
  const int bid = blockIdx.x;
  const int tid = threadIdx.x;
  if (bid < 96) {
    int job = bid * 4 + (tid >> 6);   // 0..383
    int l   = tid & 63;
    int kk  = job >> 4;               // 0..23
    int cb  = job & 15;               // 0..15
    int a   = cb * 16 + (l & 15);
    int k0  = kk * 32 + (l >> 4) * 8;
    bf16x8 pk;
#pragma unroll
    for (int j = 0; j < 8; ++j) pk[j] = (__bf16)W[(k0 + j) * An + a];
    *(bf16x8*)(pw + ((size_t)(job * 64 + l)) * 8) = pk;
  } else {
    __shared__ int scan[256];
    const int b = bid - 96;
    const int* mrow = mask + (size_t)b * Sn;
    int loc[8], lc = 0;
#pragma unroll
    for (int k = 0; k < 8; ++k) {
      loc[k] = mrow[tid * 8 + k];
      lc += loc[k];
    }
    scan[tid] = lc;
    __syncthreads();
    for (int off = 1; off < 256; off <<= 1) {
      int v = scan[tid];
      int add = (tid >= off) ? scan[tid - off] : 0;
      __syncthreads();
      scan[tid] = v + add;
      __syncthreads();
    }
    int o = scan[tid] - lc;           // exclusive prefix
    int* rb = ridx + (size_t)b * Sn;
#pragma unroll
    for (int k = 0; k < 8; ++k)
      if (loc[k]) rb[o++] = tid * 8 + k;
    if (tid == 255) count[b] = scan[255];
  }
}

// ---------------- main fused kernel (R16 structure, active rows only) ----------------
// grid = 4096 slots; slot (b, ci) processes active rows [ci*32, ci*32+32) of
// batch b via the compacted index list; slots past count[b] exit immediately.
// Staging: batch-issued 24 float4/thread (R11-proven) through the row gather.
// K-loop: wf[4][4] depth-4 W register rotation (R10-proven).
__launch_bounds__(256, 3)
__global__ void attn_pool_main(const float* __restrict__ x,
                               const unsigned short* __restrict__ pw,
                               const float* __restrict__ bias,
                               const float* __restrict__ u,
                               const int* __restrict__ ridx,
                               const int* __restrict__ count,
                               float* __restrict__ outpart,
                               float* __restrict__ sumpart) {
  __shared__ __align__(16) char xs[49152];   // 32 rows x 768 bf16, XOR-swizzled
  __shared__ float aitp[128];
  __shared__ float aitv[32];
  __shared__ int rows[32];

  const int tid  = threadIdx.x;
  const int lane = tid & 63;
  const int w    = tid >> 6;      // wave 0..3, cols w*64..w*64+63
  const int cid  = blockIdx.x;
  const int b    = cid >> 6;
  const int ci   = cid & 63;
  const int base = ci * ROWS;
  const int ntot = count[b];
  if (base >= ntot) return;                    // inactive slot
  const int nact = min(ROWS, ntot - base);

  if (tid < 32)
    rows[tid] = ridx[(size_t)b * Sn + base + ((tid < nact) ? tid : 0)];
  __syncthreads();

  // ---- stage x tile: 32 gathered rows x 768 fp32 -> bf16 LDS (swizzled) ----
  const float* xbb = x + (size_t)b * Sn * Dn;
  {
    float4 ldA[12], ldB[12];
#pragma unroll
    for (int j = 0; j < 12; ++j) {
      int unit = tid + j * 256;       // 0..3071 ; 8 k-elems each
      int row  = unit / 96;
      int ku   = unit % 96;
      const float4* g = (const float4*)(xbb + (size_t)rows[row] * Dn + ku * 8);
      ldA[j] = g[0];
      ldB[j] = g[1];
    }
    __builtin_amdgcn_sched_barrier(0);   // keep all 24 loads issued up-front
#pragma unroll
    for (int j = 0; j < 12; ++j) {
      int unit = tid + j * 256;
      int row  = unit / 96;
      int ku   = unit % 96;
      bf16x8 pk;
      pk[0] = (__bf16)ldA[j].x; pk[1] = (__bf16)ldA[j].y;
      pk[2] = (__bf16)ldA[j].z; pk[3] = (__bf16)ldA[j].w;
      pk[4] = (__bf16)ldB[j].x; pk[5] = (__bf16)ldB[j].y;
      pk[6] = (__bf16)ldB[j].z; pk[7] = (__bf16)ldB[j].w;
      int off = (row * 1536 + ku * 16) ^ ((row & 7) << 4);
      *(bf16x8*)(xs + off) = pk;
    }
  }

  const int arow  = lane & 15;
  const int kh16  = (lane >> 4) * 16;
  const int swz   = (arow & 7) << 4;
  const char* wlane = (const char*)pw + (size_t)(w * 4) * 1024 + (size_t)lane * 16;

  // ---- W pipeline prologue: load kk=0..3 into wf (ld regs dead now) ----
  bf16x8 wf[4][4];
#pragma unroll
  for (int s = 0; s < 4; ++s) {
    const char* wk = wlane + (size_t)s * 16384;
    wf[s][0] = *(const bf16x8*)(wk);
    wf[s][1] = *(const bf16x8*)(wk + 1024);
    wf[s][2] = *(const bf16x8*)(wk + 2048);
    wf[s][3] = *(const bf16x8*)(wk + 3072);
  }

  asm volatile("s_waitcnt lgkmcnt(0)" ::: "memory");
  __builtin_amdgcn_s_barrier();     // xs published; wf stream in flight

  f32x4 acc[2][4];
#pragma unroll
  for (int p = 0; p < 2; ++p)
#pragma unroll
    for (int q = 0; q < 4; ++q) acc[p][q] = (f32x4){0.f, 0.f, 0.f, 0.f};

  // ---- K-loop: use wf[kk&3], reload it for kk+4 (counted vmcnt waits) ----
#pragma unroll
  for (int kk = 0; kk < NK; ++kk) {
    const int s = kk & 3;
    bf16x8 a0 = *(const bf16x8*)(xs + ((arow * 1536 + kk * 64 + kh16) ^ swz));
    bf16x8 a1 = *(const bf16x8*)(xs + (((arow + 16) * 1536 + kk * 64 + kh16) ^ swz));
    bf16x8 b0 = wf[s][0], b1 = wf[s][1], b2 = wf[s][2], b3 = wf[s][3];
    if (kk + 4 < NK) {
      const char* wk = wlane + (size_t)(kk + 4) * 16384;
      wf[s][0] = *(const bf16x8*)(wk);
      wf[s][1] = *(const bf16x8*)(wk + 1024);
      wf[s][2] = *(const bf16x8*)(wk + 2048);
      wf[s][3] = *(const bf16x8*)(wk + 3072);
    }
    acc[0][0] = __builtin_amdgcn_mfma_f32_16x16x32_bf16(a0, b0, acc[0][0], 0, 0, 0);
    acc[1][0] = __builtin_amdgcn_mfma_f32_16x16x32_bf16(a1, b0, acc[1][0], 0, 0, 0);
    acc[0][1] = __builtin_amdgcn_mfma_f32_16x16x32_bf16(a0, b1, acc[0][1], 0, 0, 0);
    acc[1][1] = __builtin_amdgcn_mfma_f32_16x16x32_bf16(a1, b1, acc[1][1], 0, 0, 0);
    acc[0][2] = __builtin_amdgcn_mfma_f32_16x16x32_bf16(a0, b2, acc[0][2], 0, 0, 0);
    acc[1][2] = __builtin_amdgcn_mfma_f32_16x16x32_bf16(a1, b2, acc[1][2], 0, 0, 0);
    acc[0][3] = __builtin_amdgcn_mfma_f32_16x16x32_bf16(a0, b3, acc[0][3], 0, 0, 0);
    acc[1][3] = __builtin_amdgcn_mfma_f32_16x16x32_bf16(a1, b3, acc[1][3], 0, 0, 0);
  }

  // ---- epilogue: tanh + dot with u -> per-row partials ----
  float rowp[8];
#pragma unroll
  for (int p = 0; p < 8; ++p) rowp[p] = 0.f;
#pragma unroll
  for (int cbi = 0; cbi < 4; ++cbi) {
    int col = w * 64 + cbi * 16 + arow;
    float bia = bias[col];
    float uv  = u[col];
#pragma unroll
    for (int rb = 0; rb < 2; ++rb) {
#pragma unroll
      for (int r = 0; r < 4; ++r) {
        float v = acc[rb][cbi][r] + bia;
        v = fminf(fmaxf(v, -15.f), 15.f);
        float e2 = __expf(2.f * v);
        float th = (e2 - 1.f) * __builtin_amdgcn_rcpf(e2 + 1.f);
        rowp[rb * 4 + r] += th * uv;
      }
    }
  }
#pragma unroll
  for (int m = 1; m < 16; m <<= 1)
#pragma unroll
    for (int p = 0; p < 8; ++p) rowp[p] += __shfl_xor(rowp[p], m, 64);

  if (arow == 0) {
    int rbase = (lane >> 4) * 4;
#pragma unroll
    for (int rb = 0; rb < 2; ++rb)
#pragma unroll
      for (int r = 0; r < 4; ++r)
        aitp[w * 32 + rb * 16 + rbase + r] = rowp[rb * 4 + r];
  }
  __syncthreads();

  // ---- ait = exp(sum) for active rows, 0 for pad ; chunk sum ----
  if (tid < 32) {
    float s = aitp[tid] + aitp[32 + tid] + aitp[64 + tid] + aitp[96 + tid];
    float av = (tid < nact) ? __expf(s) : 0.f;
    aitv[tid] = av;
    float t = av;
#pragma unroll
    for (int m = 1; m < 32; m <<= 1) t += __shfl_xor(t, m, 64);
    if (tid == 0) sumpart[cid] = t;
  }
  __syncthreads();

  // ---- pooling: 192 threads, 2 row-groups of 16 rows ----
  float pac[8];
#pragma unroll
  for (int e = 0; e < 8; ++e) pac[e] = 0.f;
  int rg = tid / 96;              // 0..1 for tid<192
  int du = tid % 96;              // 8-d unit
  if (tid < 192) {
#pragma unroll
    for (int rr = 0; rr < 16; ++rr) {
      int row = rg * 16 + rr;
      int off = (row * 1536 + du * 16) ^ ((row & 7) << 4);
      bf16x8 xv = *(const bf16x8*)(xs + off);
      float a = aitv[row];
#pragma unroll
      for (int e = 0; e < 8; ++e) pac[e] += a * (float)xv[e];
    }
  }
  __syncthreads();   // all xs reads done -> safe to overlay outred onto xs

  float* outred = (float*)xs;     // [2][768] overlay
  if (tid < 192) {
#pragma unroll
    for (int e = 0; e < 8; ++e) outred[rg * 768 + du * 8 + e] = pac[e];
  }
  __syncthreads();

  {
    float* op = outpart + (size_t)cid * Dn;
#pragma unroll
    for (int j = 0; j < 3; ++j) {
      int d = tid + j * 256;
      op[d] = outred[d] + outred[768 + d];
    }
  }
}

// ---------------- finalize: out[b,d] = sum over written chunks / (sum + eps) ----
// grid = 64 b x 12 slabs of 64 d; 4 c-groups per block -> <=16 independent
// strided loads per thread (latency-hidden), then 4-way LDS reduce.
__global__ void finalize_kernel(const float* __restrict__ outpart,
                                const float* __restrict__ sumpart,
                                const int* __restrict__ count,
                                float* __restrict__ out) {
  __shared__ float red[4][64];
  __shared__ float sh;
  int b = blockIdx.x / 12, slab = blockIdx.x % 12;
  int tid = threadIdx.x;
  const int nch = (count[b] + ROWS - 1) / ROWS;   // written chunk slots
  if (tid < 64) {
    float v = (tid < nch) ? sumpart[b * 64 + tid] : 0.f;
#pragma unroll
    for (int m = 1; m < 64; m <<= 1) v += __shfl_xor(v, m, 64);
    if (tid == 0) sh = v + EPSF;
  }
  int d  = slab * 64 + (tid & 63);
  int cg = tid >> 6;                // 0..3
  const float* p = outpart + (size_t)b * 64 * Dn + d;
  float s = 0.f;
  for (int c = cg; c < nch; c += 4) s += p[(size_t)c * Dn];
  red[cg][tid & 63] = s;
  __syncthreads();
  if (tid < 64) {
    float tot = red[0][tid] + red[1][tid] + red[2][tid] + red[3][tid];
    out[(size_t)b * Dn + d] = tot / sh;
  }
}

extern "C" void kernel_launch(void* const* d_in, const int* in_sizes, int n_in,
                              void* d_out, int out_size, void* d_ws, size_t ws_size,
                              hipStream_t stream) {
  const float* x    = (const float*)d_in[0];
  const float* W    = (const float*)d_in[1];
  const float* bias = (const float*)d_in[2];
  const float* u    = (const float*)d_in[3];
  const int*   mask = (const int*)d_in[4];
  float* out = (float*)d_out;

  unsigned short* pw = (unsigned short*)d_ws;                       // 384 KB
  float* outpart = (float*)((char*)d_ws + 393216);                  // 12.58 MB
  float* sumpart = (float*)((char*)d_ws + 393216 + 12582912);       // 16 KB
  int*   ridx    = (int*)((char*)d_ws + 393216 + 12582912 + 16384); // 512 KB
  int*   count   = (int*)((char*)d_ws + 393216 + 12582912 + 16384 + 524288); // 256 B

  hipLaunchKernelGGL(prep_kernel, dim3(160), dim3(256), 0, stream,
                     W, pw, mask, ridx, count);
  hipLaunchKernelGGL(attn_pool_main, dim3(Bn * 64), dim3(256), 0, stream,
                     x, pw, bias, u, ridx, count, outpart, sumpart);
  hipLaunchKernelGGL(finalize_kernel, dim3(Bn * 12), dim3(256), 0, stream,
                     outpart, sumpart, count, out);
}